// Round 18
// baseline (55.570 us; speedup 1.0000x reference)
//
#include <hip/hip_runtime.h>

#define SUBS  64
#define GUARD 256              // left guard halves (32 tiles) [fallback path]
#define LB    32               // IIR block length (rows per run/wave)
#define JT    8                // history terms: 8*32 = 256 >= 200-tap support
#define LSTR  136              // k_mm LDS row stride (halves)

typedef _Float16 f16x8 __attribute__((ext_vector_type(8)));
typedef float    f32x4 __attribute__((ext_vector_type(4)));

__device__ inline f16x8 ld_frag(const float* p) {
    float4 a = *(const float4*)p;
    float4 b = *(const float4*)(p + 4);
    f16x8 f;
    f[0]=(_Float16)a.x; f[1]=(_Float16)a.y; f[2]=(_Float16)a.z; f[3]=(_Float16)a.w;
    f[4]=(_Float16)b.x; f[5]=(_Float16)b.y; f[6]=(_Float16)b.z; f[7]=(_Float16)b.w;
    return f;
}
__device__ inline uint pkh2(float a, float b) {
    union { _Float16 h[2]; uint u; } p;
    p.h[0] = (_Float16)a; p.h[1] = (_Float16)b; return p.u;
}

// IIR core: per basis, z[m] = 2r z[m-1] - r^2 z[m-2] + cr*x[m-1]
#define STEP3(u)                                                                 \
    _Pragma("unroll")                                                            \
    for (int b = 0; b < 3; ++b) {                                                \
        const float yn = fmaf(twr[b], y1[b], fmaf(mr2[b], y2[b], cr[b] * (u)));  \
        y2[b] = y1[b]; y1[b] = yn;                                               \
    }
#define PAIRW(wrd) {                                                             \
    union { uint u; _Float16 h[2]; } w_; w_.u = (wrd);                           \
    STEP3((float)w_.h[0]);                                                       \
    STEP3((float)w_.h[1]); }

// ---------------------------------------------------------------------------
// Kernel 1 (R15 form): MFMA Zc=(Z@C^T), Yc=(Y@C^T) (f16) into transposed
// tiled layout [tile][64 s][8 halves]; fused from-rest 32-step state run per
// wave (straight from LDS) -> packed fb[run][lane][8]. NO S here (R17 lesson:
// fragment-pattern S loads cost k_mm +16us). Tail tiles zero-filled.
// ---------------------------------------------------------------------------
__global__ __launch_bounds__(256, 4) void k_mm(
    const float* __restrict__ Z, const float* __restrict__ Y,
    const float* __restrict__ C,
    const float* __restrict__ K_spike, const float* __restrict__ tau_spike,
    const float* __restrict__ delta_spike,
    _Float16* __restrict__ Zt, _Float16* __restrict__ Yt,
    float* __restrict__ fb, int T, int rgz, int NB)
{
    __shared__ _Float16 ztl[SUBS * LSTR];
    __shared__ _Float16 ytl[SUBS * LSTR];
    const int tid  = threadIdx.x;
    const int lane = tid & 63;
    const int wv   = tid >> 6;
    const int lr   = lane & 15;
    const int lg   = lane >> 4;
    const int t0b  = blockIdx.x * 128;

    int dl = (int)rintf(delta_spike[lane]);
    dl = min(max(dl, 0), 30);
    const bool alldl0 = __all(dl == 0);

    if (blockIdx.x == 0) {                    // fb guard runs (-8..-1)
        for (int idx = tid; idx < JT * 512; idx += 256) fb[idx] = 0.f;
    }
    if (!alldl0) {                            // guards only for fallback path
        if (blockIdx.x < 8) {
            const int tile = blockIdx.x * 4 + wv;
            uint4 z4 = {0, 0, 0, 0};
            ((uint4*)Zt)[(size_t)tile * 64 + lane] = z4;
            ((uint4*)Yt)[(size_t)tile * 64 + lane] = z4;
        } else if (blockIdx.x < 18) {
            const int tile = rgz + (blockIdx.x - 8) * 4 + wv;
            uint4 z4 = {0, 0, 0, 0};
            ((uint4*)Zt)[(size_t)tile * 64 + lane] = z4;
            ((uint4*)Yt)[(size_t)tile * 64 + lane] = z4;
        }
    }

    f16x8 bfr[4][2];
    #pragma unroll
    for (int nt = 0; nt < 4; ++nt)
        #pragma unroll
        for (int ks = 0; ks < 2; ++ks)
            bfr[nt][ks] = ld_frag(&C[(lr + 16 * nt) * 64 + ks * 32 + lg * 8]);

    #pragma unroll
    for (int g = 0; g < 2; ++g) {
        const int t0 = t0b + wv * 32 + g * 16;
        const int rowA = t0 + lr;
        const bool okA = rowA < T;
        f16x8 az[2], ay[2];
        #pragma unroll
        for (int ks = 0; ks < 2; ++ks) {
            if (okA) {
                az[ks] = ld_frag(&Z[(size_t)rowA * 64 + ks * 32 + lg * 8]);
                ay[ks] = ld_frag(&Y[(size_t)rowA * 64 + ks * 32 + lg * 8]);
            } else {
                az[ks] = (f16x8)(_Float16)0.f;
                ay[ks] = (f16x8)(_Float16)0.f;
            }
        }

        f32x4 accZ[4], accY[4];
        #pragma unroll
        for (int nt = 0; nt < 4; ++nt) { accZ[nt] = (f32x4){0,0,0,0}; accY[nt] = (f32x4){0,0,0,0}; }
        #pragma unroll
        for (int nt = 0; nt < 4; ++nt) {
            #pragma unroll
            for (int ks = 0; ks < 2; ++ks) {
                accZ[nt] = __builtin_amdgcn_mfma_f32_16x16x32_f16(az[ks], bfr[nt][ks], accZ[nt], 0, 0, 0);
                accY[nt] = __builtin_amdgcn_mfma_f32_16x16x32_f16(ay[ks], bfr[nt][ks], accY[nt], 0, 0, 0);
            }
        }

        #pragma unroll
        for (int nt = 0; nt < 4; ++nt) {
            const int sc = lr + 16 * nt;
            const int lt = wv * 32 + g * 16 + lg * 4;
            uint2 pz, py;
            pz.x = pkh2(accZ[nt][0], accZ[nt][1]);
            pz.y = pkh2(accZ[nt][2], accZ[nt][3]);
            py.x = pkh2(accY[nt][0], accY[nt][1]);
            py.y = pkh2(accY[nt][2], accY[nt][3]);
            *(uint2*)&ztl[sc * LSTR + lt] = pz;
            *(uint2*)&ytl[sc * LSTR + lt] = py;
        }
    }

    __syncthreads();

    // fused from-rest state run first (serial chain overlaps store latency)
    const int grun = blockIdx.x * 4 + wv;
    if (grun < NB) {
        float twr[3], mr2[3], cr[3];
        #pragma unroll
        for (int b = 0; b < 3; ++b) {
            const float tau = __expf(tau_spike[b]);
            const float r   = __expf(-1.0f / tau);
            twr[b] = 2.0f * r;
            mr2[b] = -r * r;
            cr[b]  = K_spike[lane * 3 + b] / tau * r;
        }
        const uint* zr = (const uint*)ztl + lane * (LSTR / 2) + wv * 16;
        float y1[3] = {0.f, 0.f, 0.f}, y2[3] = {0.f, 0.f, 0.f};
        #pragma unroll
        for (int k = 0; k < 16; ++k) PAIRW(zr[k]);
        float* fout = fb + (size_t)(grun + JT) * 512 + lane * 8;
        *(float4*)fout       = make_float4(y1[0], y2[0], y1[1], y2[1]);
        *(float2*)(fout + 4) = make_float2(y1[2], y2[2]);
    }

    // cooperative tiled stores (row = s fastest -> coalesced); tail zero-fill
    const int gbase = (GUARD >> 3) + blockIdx.x * 16;
    #pragma unroll
    for (int it = 0; it < 4; ++it) {
        const int chunk = it * 256 + tid;
        const int row = chunk & 63;
        const int col = chunk >> 6;
        const int tb  = t0b + col * 8;
        if (tb + 7 < T) {
            ((uint4*)Zt)[(size_t)(gbase + col) * 64 + row] =
                *(const uint4*)&ztl[row * LSTR + col * 8];
            ((uint4*)Yt)[(size_t)(gbase + col) * 64 + row] =
                *(const uint4*)&ytl[row * LSTR + col * 8];
        } else {
            union { ushort u[8]; uint4 v; } vz, vy;
            #pragma unroll
            for (int h = 0; h < 8; ++h) {
                const bool ok = (tb + h < T);
                vz.u[h] = ok ? ((const ushort*)ztl)[row * LSTR + col * 8 + h] : (ushort)0;
                vy.u[h] = ok ? ((const ushort*)ytl)[row * LSTR + col * 8 + h] : (ushort)0;
            }
            ((uint4*)Zt)[(size_t)(gbase + col) * 64 + row] = vz.v;
            ((uint4*)Yt)[(size_t)(gbase + col) * 64 + row] = vy.v;
        }
    }
}

// ---------------------------------------------------------------------------
// Kernel 2: compose v[32i] = sum_{j=1..8} M^{32(j-1)} f_{i-j} (Horner,
// closed-form M^32) from PACKED fb (16 wide loads), then 30 steps over 4
// aligned x tiles; out = sigmoid(Yc + S + theta + filtered)*W + Vo.
// S packed early (coalesced 256B/instr), latency hides under the Horner.
// ---------------------------------------------------------------------------
#define EMIT(o, f) {                                                             \
    const int t_ = t0 + (o);                                                     \
    if (t_ < T) {                                                                \
        union { uint u; _Float16 h[2]; } wy_; wy_.u = ywd[(o) >> 1];             \
        union { uint u; _Float16 h[2]; } wp_; wp_.u = spk[(o) >> 1];             \
        const float xin_ = (float)wy_.h[(o) & 1] + (float)wp_.h[(o) & 1] + (f);  \
        const float sig_ = 1.0f / (1.0f + __expf(-xin_));                        \
        out[(size_t)t_ * 64 + s] = fmaf(sig_, wsub, vo);                         \
    } }

__global__ __launch_bounds__(256, 4) void k_iir2(
    const _Float16* __restrict__ Zt, const _Float16* __restrict__ Yt,
    const float* __restrict__ S,
    const float* __restrict__ K_spike, const float* __restrict__ tau_spike,
    const float* __restrict__ delta_spike, const float* __restrict__ theta,
    const float* __restrict__ W, const float* __restrict__ Vo,
    const float* __restrict__ fb, float* __restrict__ out, int T, int NB)
{
    const int tid = threadIdx.x;
    const int s   = tid & 63;
    const int wv  = tid >> 6;
    const int i   = blockIdx.x * 4 + wv;
    if (i >= NB) return;
    const int t0 = i * LB;

    float twr[3], mr2[3], cr[3], taus[3];
    #pragma unroll
    for (int b = 0; b < 3; ++b) {
        const float tau = __expf(tau_spike[b]);
        taus[b] = tau;
        const float r = __expf(-1.0f / tau);
        twr[b] = 2.0f * r;
        mr2[b] = -r * r;
        cr[b]  = K_spike[s * 3 + b] / tau * r;
    }
    int dl = (int)rintf(delta_spike[s]);
    dl = min(max(dl, 0), 30);
    const float th   = theta[s];
    const float wsub = W[s];
    const float vo   = Vo[0];

    if (__all(dl == 0)) {
        // pack S + theta early (coalesced; latency hides under the Horner)
        uint spk[16];
        #pragma unroll
        for (int p = 0; p < 16; ++p) {
            const int t1 = min(t0 + 2 * p,     T - 1);
            const int t2 = min(t0 + 2 * p + 1, T - 1);
            spk[p] = pkh2(S[(size_t)t1 * 64 + s] + th, S[(size_t)t2 * 64 + s] + th);
        }

        // M^32 per basis: z[n+k] = (k+1) r^k z[n] - k r^(k+1) z[n-1]
        float aL[3], bL[3], cL[3], dL[3];
        #pragma unroll
        for (int b = 0; b < 3; ++b) {
            const float r   = 0.5f * twr[b];
            const float rm1 = __expf(-(float)(LB - 1) / taus[b]);  // r^31
            const float rl  = rm1 * r;                             // r^32
            const float rp  = rl * r;                              // r^33
            aL[b] = (float)(LB + 1) * rl;
            bL[b] = -(float)LB * rp;
            cL[b] = (float)LB * rm1;
            dL[b] = -(float)(LB - 1) * rl;
        }
        float y1[3], y2[3];
        {   // f_{i-8}
            const float* fq = fb + (size_t)i * 512 + s * 8;
            const float4 lo = *(const float4*)fq;
            const float2 hi = *(const float2*)(fq + 4);
            y1[0] = lo.x; y2[0] = lo.y; y1[1] = lo.z; y2[1] = lo.w;
            y1[2] = hi.x; y2[2] = hi.y;
        }
        #pragma unroll
        for (int j = 7; j >= 1; --j) {
            const float* fq = fb + (size_t)(i + JT - j) * 512 + s * 8;
            const float4 lo = *(const float4*)fq;
            const float2 hi = *(const float2*)(fq + 4);
            const float f1[3] = { lo.x, lo.z, hi.x };
            const float f2[3] = { lo.y, lo.w, hi.y };
            #pragma unroll
            for (int b = 0; b < 3; ++b) {
                const float n1 = fmaf(aL[b], y1[b], fmaf(bL[b], y2[b], f1[b]));
                const float n2 = fmaf(cL[b], y1[b], fmaf(dL[b], y2[b], f2[b]));
                y1[b] = n1; y2[b] = n2;
            }
        }

        const uint4* xb = (const uint4*)Zt + (size_t)(32 + 4 * i) * 64 + s;
        const uint4 x0 = xb[0], x1 = xb[64], x2 = xb[128], x3 = xb[192];
        const uint4* yb = (const uint4*)Yt + (size_t)(32 + 4 * i) * 64 + s;
        const uint4 yv0 = yb[0], yv1 = yb[64], yv2 = yb[128], yv3 = yb[192];

        const uint xw[15]  = { x0.x, x0.y, x0.z, x0.w, x1.x, x1.y, x1.z, x1.w,
                               x2.x, x2.y, x2.z, x2.w, x3.x, x3.y, x3.z };
        const uint ywd[16] = { yv0.x, yv0.y, yv0.z, yv0.w, yv1.x, yv1.y, yv1.z, yv1.w,
                               yv2.x, yv2.y, yv2.z, yv2.w, yv3.x, yv3.y, yv3.z, yv3.w };

        EMIT(0, y2[0] + y2[1] + y2[2]);
        EMIT(1, y1[0] + y1[1] + y1[2]);
        #pragma unroll
        for (int w = 0; w < 15; ++w) {
            union { uint u; _Float16 h[2]; } wx; wx.u = xw[w];
            STEP3((float)wx.h[0]);
            EMIT(2 + 2 * w, y1[0] + y1[1] + y1[2]);
            STEP3((float)wx.h[1]);
            EMIT(3 + 2 * w, y1[0] + y1[1] + y1[2]);
        }
    } else {
        // generic per-lane-delay path (correct, slow; unused for bench data)
        float y1[3] = {0.f, 0.f, 0.f}, y2[3] = {0.f, 0.f, 0.f};
        const int xi0 = t0 - 226 - dl;
        for (int k = 0; k < 224 + LB; ++k) {
            const int h = GUARD + xi0 + k;
            const float u = (float)Zt[(size_t)(h >> 3) * 512 + s * 8 + (h & 7)];
            STEP3(u);
            const int o = k - 224;
            if (o >= 0) {
                const int t = t0 + o;
                if (t < T) {
                    const int hy = GUARD + t;
                    const float yc = (float)Yt[(size_t)(hy >> 3) * 512 + s * 8 + (hy & 7)];
                    const float xin = yc + S[(size_t)t * 64 + s] + th
                                      + y1[0] + y1[1] + y1[2];
                    const float sig = 1.0f / (1.0f + __expf(-xin));
                    out[(size_t)t * 64 + s] = fmaf(sig, wsub, vo);
                }
            }
        }
    }
}

// ---------------------------------------------------------------------------
extern "C" void kernel_launch(void* const* d_in, const int* in_sizes, int n_in,
                              void* d_out, int out_size, void* d_ws, size_t ws_size,
                              hipStream_t stream)
{
    const float* S     = (const float*)d_in[0];
    const float* Y     = (const float*)d_in[1];
    const float* Z     = (const float*)d_in[2];
    const float* C     = (const float*)d_in[3];
    const float* Vo    = (const float*)d_in[4];
    const float* W     = (const float*)d_in[5];
    const float* theta = (const float*)d_in[6];
    const float* K     = (const float*)d_in[7];
    const float* tau   = (const float*)d_in[8];
    const float* delta = (const float*)d_in[9];
    const int T  = in_sizes[0] / SUBS;
    const int NB = (T + LB - 1) / LB;

    const int rgz    = (GUARD + T + 7) >> 3;
    const int ntiles = rgz + 44;
    _Float16* Zt = (_Float16*)d_ws;
    _Float16* Yt = (_Float16*)((char*)d_ws + (size_t)ntiles * 1024);
    float*    fb = (float*)((char*)d_ws + (size_t)ntiles * 2048);

    k_mm<<<(T + 127) / 128, 256, 0, stream>>>(Z, Y, C, K, tau, delta,
                                              Zt, Yt, fb, T, rgz, NB);
    k_iir2<<<(NB + 3) / 4, 256, 0, stream>>>(Zt, Yt, S, K, tau, delta, theta,
                                             W, Vo, fb, (float*)d_out, T, NB);
}

// Round 19
// 48.846 us; speedup vs baseline: 1.1376x; 1.1376x over previous
//
#include <hip/hip_runtime.h>

#define SUBS  64
#define GUARD 256              // left guard halves (32 tiles) [fallback path]
#define LB    32               // IIR block length (rows per run/wave)
#define JT    8                // history terms: 8*32 = 256 >= 200-tap support
#define LSTR  136              // k_mm LDS row stride (halves)

typedef _Float16 f16x8 __attribute__((ext_vector_type(8)));
typedef float    f32x4 __attribute__((ext_vector_type(4)));

__device__ inline f16x8 ld_frag(const float* p) {
    float4 a = *(const float4*)p;
    float4 b = *(const float4*)(p + 4);
    f16x8 f;
    f[0]=(_Float16)a.x; f[1]=(_Float16)a.y; f[2]=(_Float16)a.z; f[3]=(_Float16)a.w;
    f[4]=(_Float16)b.x; f[5]=(_Float16)b.y; f[6]=(_Float16)b.z; f[7]=(_Float16)b.w;
    return f;
}
__device__ inline uint pkh2(float a, float b) {
    union { _Float16 h[2]; uint u; } p;
    p.h[0] = (_Float16)a; p.h[1] = (_Float16)b; return p.u;
}

// IIR core: per basis, z[m] = 2r z[m-1] - r^2 z[m-2] + cr*x[m-1]
#define STEP3(u)                                                                 \
    _Pragma("unroll")                                                            \
    for (int b = 0; b < 3; ++b) {                                                \
        const float yn = fmaf(twr[b], y1[b], fmaf(mr2[b], y2[b], cr[b] * (u)));  \
        y2[b] = y1[b]; y1[b] = yn;                                               \
    }
#define PAIRW(wrd) {                                                             \
    union { uint u; _Float16 h[2]; } w_; w_.u = (wrd);                           \
    STEP3((float)w_.h[0]);                                                       \
    STEP3((float)w_.h[1]); }

// ---------------------------------------------------------------------------
// Kernel 1 (unchanged from R18 — measured ~14-15 us): MFMA Zc, Yc into
// transposed tiled layout [tile][64 s][8 halves]; fused from-rest 32-step
// state run per wave -> packed fb[run][lane][8]. Tail tiles zero-filled.
// ---------------------------------------------------------------------------
__global__ __launch_bounds__(256, 4) void k_mm(
    const float* __restrict__ Z, const float* __restrict__ Y,
    const float* __restrict__ C,
    const float* __restrict__ K_spike, const float* __restrict__ tau_spike,
    const float* __restrict__ delta_spike,
    _Float16* __restrict__ Zt, _Float16* __restrict__ Yt,
    float* __restrict__ fb, int T, int rgz, int NB)
{
    __shared__ _Float16 ztl[SUBS * LSTR];
    __shared__ _Float16 ytl[SUBS * LSTR];
    const int tid  = threadIdx.x;
    const int lane = tid & 63;
    const int wv   = tid >> 6;
    const int lr   = lane & 15;
    const int lg   = lane >> 4;
    const int t0b  = blockIdx.x * 128;

    int dl = (int)rintf(delta_spike[lane]);
    dl = min(max(dl, 0), 30);
    const bool alldl0 = __all(dl == 0);

    if (blockIdx.x == 0) {                    // fb guard runs (-8..-1)
        for (int idx = tid; idx < JT * 512; idx += 256) fb[idx] = 0.f;
    }
    if (!alldl0) {                            // guards only for fallback path
        if (blockIdx.x < 8) {
            const int tile = blockIdx.x * 4 + wv;
            uint4 z4 = {0, 0, 0, 0};
            ((uint4*)Zt)[(size_t)tile * 64 + lane] = z4;
            ((uint4*)Yt)[(size_t)tile * 64 + lane] = z4;
        } else if (blockIdx.x < 18) {
            const int tile = rgz + (blockIdx.x - 8) * 4 + wv;
            uint4 z4 = {0, 0, 0, 0};
            ((uint4*)Zt)[(size_t)tile * 64 + lane] = z4;
            ((uint4*)Yt)[(size_t)tile * 64 + lane] = z4;
        }
    }

    f16x8 bfr[4][2];
    #pragma unroll
    for (int nt = 0; nt < 4; ++nt)
        #pragma unroll
        for (int ks = 0; ks < 2; ++ks)
            bfr[nt][ks] = ld_frag(&C[(lr + 16 * nt) * 64 + ks * 32 + lg * 8]);

    #pragma unroll
    for (int g = 0; g < 2; ++g) {
        const int t0 = t0b + wv * 32 + g * 16;
        const int rowA = t0 + lr;
        const bool okA = rowA < T;
        f16x8 az[2], ay[2];
        #pragma unroll
        for (int ks = 0; ks < 2; ++ks) {
            if (okA) {
                az[ks] = ld_frag(&Z[(size_t)rowA * 64 + ks * 32 + lg * 8]);
                ay[ks] = ld_frag(&Y[(size_t)rowA * 64 + ks * 32 + lg * 8]);
            } else {
                az[ks] = (f16x8)(_Float16)0.f;
                ay[ks] = (f16x8)(_Float16)0.f;
            }
        }

        f32x4 accZ[4], accY[4];
        #pragma unroll
        for (int nt = 0; nt < 4; ++nt) { accZ[nt] = (f32x4){0,0,0,0}; accY[nt] = (f32x4){0,0,0,0}; }
        #pragma unroll
        for (int nt = 0; nt < 4; ++nt) {
            #pragma unroll
            for (int ks = 0; ks < 2; ++ks) {
                accZ[nt] = __builtin_amdgcn_mfma_f32_16x16x32_f16(az[ks], bfr[nt][ks], accZ[nt], 0, 0, 0);
                accY[nt] = __builtin_amdgcn_mfma_f32_16x16x32_f16(ay[ks], bfr[nt][ks], accY[nt], 0, 0, 0);
            }
        }

        #pragma unroll
        for (int nt = 0; nt < 4; ++nt) {
            const int sc = lr + 16 * nt;
            const int lt = wv * 32 + g * 16 + lg * 4;
            uint2 pz, py;
            pz.x = pkh2(accZ[nt][0], accZ[nt][1]);
            pz.y = pkh2(accZ[nt][2], accZ[nt][3]);
            py.x = pkh2(accY[nt][0], accY[nt][1]);
            py.y = pkh2(accY[nt][2], accY[nt][3]);
            *(uint2*)&ztl[sc * LSTR + lt] = pz;
            *(uint2*)&ytl[sc * LSTR + lt] = py;
        }
    }

    __syncthreads();

    // fused from-rest state run first (serial chain overlaps store latency)
    const int grun = blockIdx.x * 4 + wv;
    if (grun < NB) {
        float twr[3], mr2[3], cr[3];
        #pragma unroll
        for (int b = 0; b < 3; ++b) {
            const float tau = __expf(tau_spike[b]);
            const float r   = __expf(-1.0f / tau);
            twr[b] = 2.0f * r;
            mr2[b] = -r * r;
            cr[b]  = K_spike[lane * 3 + b] / tau * r;
        }
        const uint* zr = (const uint*)ztl + lane * (LSTR / 2) + wv * 16;
        float y1[3] = {0.f, 0.f, 0.f}, y2[3] = {0.f, 0.f, 0.f};
        #pragma unroll
        for (int k = 0; k < 16; ++k) PAIRW(zr[k]);
        float* fout = fb + (size_t)(grun + JT) * 512 + lane * 8;
        *(float4*)fout       = make_float4(y1[0], y2[0], y1[1], y2[1]);
        *(float2*)(fout + 4) = make_float2(y1[2], y2[2]);
    }

    // cooperative tiled stores (row = s fastest -> coalesced); tail zero-fill
    const int gbase = (GUARD >> 3) + blockIdx.x * 16;
    #pragma unroll
    for (int it = 0; it < 4; ++it) {
        const int chunk = it * 256 + tid;
        const int row = chunk & 63;
        const int col = chunk >> 6;
        const int tb  = t0b + col * 8;
        if (tb + 7 < T) {
            ((uint4*)Zt)[(size_t)(gbase + col) * 64 + row] =
                *(const uint4*)&ztl[row * LSTR + col * 8];
            ((uint4*)Yt)[(size_t)(gbase + col) * 64 + row] =
                *(const uint4*)&ytl[row * LSTR + col * 8];
        } else {
            union { ushort u[8]; uint4 v; } vz, vy;
            #pragma unroll
            for (int h = 0; h < 8; ++h) {
                const bool ok = (tb + h < T);
                vz.u[h] = ok ? ((const ushort*)ztl)[row * LSTR + col * 8 + h] : (ushort)0;
                vy.u[h] = ok ? ((const ushort*)ytl)[row * LSTR + col * 8 + h] : (ushort)0;
            }
            ((uint4*)Zt)[(size_t)(gbase + col) * 64 + row] = vz.v;
            ((uint4*)Yt)[(size_t)(gbase + col) * 64 + row] = vy.v;
        }
    }
}

// ---------------------------------------------------------------------------
// Kernel 2: Horner-compose v[32i] from packed fb (16 wide loads), then 30
// steps over 4 aligned x tiles; out = sigmoid(Yc + S + theta + filt)*W + Vo.
// launch_bounds(256,3): at (256,4) the allocator pins 64 VGPR and spills
// ~20 words/thread (R18: WRITE 50000 KB, 40.6 us); (256,3) historically
// allocates 84 VGPR clean (R12/R13).
// ---------------------------------------------------------------------------
#define EMIT(o, f) {                                                             \
    const int t_ = t0 + (o);                                                     \
    if (t_ < T) {                                                                \
        union { uint u; _Float16 h[2]; } wy_; wy_.u = ywd[(o) >> 1];             \
        union { uint u; _Float16 h[2]; } wp_; wp_.u = spk[(o) >> 1];             \
        const float xin_ = (float)wy_.h[(o) & 1] + (float)wp_.h[(o) & 1] + (f);  \
        const float sig_ = 1.0f / (1.0f + __expf(-xin_));                        \
        out[(size_t)t_ * 64 + s] = fmaf(sig_, wsub, vo);                         \
    } }

__global__ __launch_bounds__(256, 3) void k_iir2(
    const _Float16* __restrict__ Zt, const _Float16* __restrict__ Yt,
    const float* __restrict__ S,
    const float* __restrict__ K_spike, const float* __restrict__ tau_spike,
    const float* __restrict__ delta_spike, const float* __restrict__ theta,
    const float* __restrict__ W, const float* __restrict__ Vo,
    const float* __restrict__ fb, float* __restrict__ out, int T, int NB)
{
    const int tid = threadIdx.x;
    const int s   = tid & 63;
    const int wv  = tid >> 6;
    const int i   = blockIdx.x * 4 + wv;
    if (i >= NB) return;
    const int t0 = i * LB;

    float twr[3], mr2[3], cr[3], taus[3];
    #pragma unroll
    for (int b = 0; b < 3; ++b) {
        const float tau = __expf(tau_spike[b]);
        taus[b] = tau;
        const float r = __expf(-1.0f / tau);
        twr[b] = 2.0f * r;
        mr2[b] = -r * r;
        cr[b]  = K_spike[s * 3 + b] / tau * r;
    }
    int dl = (int)rintf(delta_spike[s]);
    dl = min(max(dl, 0), 30);
    const float th   = theta[s];
    const float wsub = W[s];
    const float vo   = Vo[0];

    if (__all(dl == 0)) {
        // pack S + theta early (coalesced; latency hides under the Horner)
        uint spk[16];
        #pragma unroll
        for (int p = 0; p < 16; ++p) {
            const int t1 = min(t0 + 2 * p,     T - 1);
            const int t2 = min(t0 + 2 * p + 1, T - 1);
            spk[p] = pkh2(S[(size_t)t1 * 64 + s] + th, S[(size_t)t2 * 64 + s] + th);
        }

        // M^32 per basis: z[n+k] = (k+1) r^k z[n] - k r^(k+1) z[n-1]
        float aL[3], bL[3], cL[3], dL[3];
        #pragma unroll
        for (int b = 0; b < 3; ++b) {
            const float r   = 0.5f * twr[b];
            const float rm1 = __expf(-(float)(LB - 1) / taus[b]);  // r^31
            const float rl  = rm1 * r;                             // r^32
            const float rp  = rl * r;                              // r^33
            aL[b] = (float)(LB + 1) * rl;
            bL[b] = -(float)LB * rp;
            cL[b] = (float)LB * rm1;
            dL[b] = -(float)(LB - 1) * rl;
        }
        float y1[3], y2[3];
        {   // f_{i-8}
            const float* fq = fb + (size_t)i * 512 + s * 8;
            const float4 lo = *(const float4*)fq;
            const float2 hi = *(const float2*)(fq + 4);
            y1[0] = lo.x; y2[0] = lo.y; y1[1] = lo.z; y2[1] = lo.w;
            y1[2] = hi.x; y2[2] = hi.y;
        }
        #pragma unroll
        for (int j = 7; j >= 1; --j) {
            const float* fq = fb + (size_t)(i + JT - j) * 512 + s * 8;
            const float4 lo = *(const float4*)fq;
            const float2 hi = *(const float2*)(fq + 4);
            const float f1[3] = { lo.x, lo.z, hi.x };
            const float f2[3] = { lo.y, lo.w, hi.y };
            #pragma unroll
            for (int b = 0; b < 3; ++b) {
                const float n1 = fmaf(aL[b], y1[b], fmaf(bL[b], y2[b], f1[b]));
                const float n2 = fmaf(cL[b], y1[b], fmaf(dL[b], y2[b], f2[b]));
                y1[b] = n1; y2[b] = n2;
            }
        }

        const uint4* xb = (const uint4*)Zt + (size_t)(32 + 4 * i) * 64 + s;
        const uint4 x0 = xb[0], x1 = xb[64], x2 = xb[128], x3 = xb[192];
        const uint4* yb = (const uint4*)Yt + (size_t)(32 + 4 * i) * 64 + s;
        const uint4 yv0 = yb[0], yv1 = yb[64], yv2 = yb[128], yv3 = yb[192];

        const uint xw[15]  = { x0.x, x0.y, x0.z, x0.w, x1.x, x1.y, x1.z, x1.w,
                               x2.x, x2.y, x2.z, x2.w, x3.x, x3.y, x3.z };
        const uint ywd[16] = { yv0.x, yv0.y, yv0.z, yv0.w, yv1.x, yv1.y, yv1.z, yv1.w,
                               yv2.x, yv2.y, yv2.z, yv2.w, yv3.x, yv3.y, yv3.z, yv3.w };

        EMIT(0, y2[0] + y2[1] + y2[2]);
        EMIT(1, y1[0] + y1[1] + y1[2]);
        #pragma unroll
        for (int w = 0; w < 15; ++w) {
            union { uint u; _Float16 h[2]; } wx; wx.u = xw[w];
            STEP3((float)wx.h[0]);
            EMIT(2 + 2 * w, y1[0] + y1[1] + y1[2]);
            STEP3((float)wx.h[1]);
            EMIT(3 + 2 * w, y1[0] + y1[1] + y1[2]);
        }
    } else {
        // generic per-lane-delay path (correct, slow; unused for bench data)
        float y1[3] = {0.f, 0.f, 0.f}, y2[3] = {0.f, 0.f, 0.f};
        const int xi0 = t0 - 226 - dl;
        for (int k = 0; k < 224 + LB; ++k) {
            const int h = GUARD + xi0 + k;
            const float u = (float)Zt[(size_t)(h >> 3) * 512 + s * 8 + (h & 7)];
            STEP3(u);
            const int o = k - 224;
            if (o >= 0) {
                const int t = t0 + o;
                if (t < T) {
                    const int hy = GUARD + t;
                    const float yc = (float)Yt[(size_t)(hy >> 3) * 512 + s * 8 + (hy & 7)];
                    const float xin = yc + S[(size_t)t * 64 + s] + th
                                      + y1[0] + y1[1] + y1[2];
                    const float sig = 1.0f / (1.0f + __expf(-xin));
                    out[(size_t)t * 64 + s] = fmaf(sig, wsub, vo);
                }
            }
        }
    }
}

// ---------------------------------------------------------------------------
extern "C" void kernel_launch(void* const* d_in, const int* in_sizes, int n_in,
                              void* d_out, int out_size, void* d_ws, size_t ws_size,
                              hipStream_t stream)
{
    const float* S     = (const float*)d_in[0];
    const float* Y     = (const float*)d_in[1];
    const float* Z     = (const float*)d_in[2];
    const float* C     = (const float*)d_in[3];
    const float* Vo    = (const float*)d_in[4];
    const float* W     = (const float*)d_in[5];
    const float* theta = (const float*)d_in[6];
    const float* K     = (const float*)d_in[7];
    const float* tau   = (const float*)d_in[8];
    const float* delta = (const float*)d_in[9];
    const int T  = in_sizes[0] / SUBS;
    const int NB = (T + LB - 1) / LB;

    const int rgz    = (GUARD + T + 7) >> 3;
    const int ntiles = rgz + 44;
    _Float16* Zt = (_Float16*)d_ws;
    _Float16* Yt = (_Float16*)((char*)d_ws + (size_t)ntiles * 1024);
    float*    fb = (float*)((char*)d_ws + (size_t)ntiles * 2048);

    k_mm<<<(T + 127) / 128, 256, 0, stream>>>(Z, Y, C, K, tau, delta,
                                              Zt, Yt, fb, T, rgz, NB);
    k_iir2<<<(NB + 3) / 4, 256, 0, stream>>>(Zt, Yt, S, K, tau, delta, theta,
                                             W, Vo, fb, (float*)d_out, T, NB);
}

// Round 20
// 47.639 us; speedup vs baseline: 1.1665x; 1.0253x over previous
//
#include <hip/hip_runtime.h>

#define SUBS  64
#define GUARD 256              // left guard halves (32 tiles) [fallback path]
#define LB    32               // IIR block length (rows per run/wave)
#define JT    8                // history terms: 8*32 = 256 >= 200-tap support
#define LSTR  136              // k_mm LDS row stride (halves)

typedef _Float16 f16x8 __attribute__((ext_vector_type(8)));
typedef float    f32x4 __attribute__((ext_vector_type(4)));

union uh2 { uint u; _Float16 h[2]; };

__device__ inline f16x8 ld_frag(const float* p) {
    float4 a = *(const float4*)p;
    float4 b = *(const float4*)(p + 4);
    f16x8 f;
    f[0]=(_Float16)a.x; f[1]=(_Float16)a.y; f[2]=(_Float16)a.z; f[3]=(_Float16)a.w;
    f[4]=(_Float16)b.x; f[5]=(_Float16)b.y; f[6]=(_Float16)b.z; f[7]=(_Float16)b.w;
    return f;
}
__device__ inline uint pkh2(float a, float b) {
    union { _Float16 h[2]; uint u; } p;
    p.h[0] = (_Float16)a; p.h[1] = (_Float16)b; return p.u;
}

// IIR core: per basis, z[m] = 2r z[m-1] - r^2 z[m-2] + cr*x[m-1]
#define STEP3(u)                                                                 \
    _Pragma("unroll")                                                            \
    for (int b = 0; b < 3; ++b) {                                                \
        const float yn = fmaf(twr[b], y1[b], fmaf(mr2[b], y2[b], cr[b] * (u)));  \
        y2[b] = y1[b]; y1[b] = yn;                                               \
    }
#define PAIRW(wrd) {                                                             \
    uh2 w_; w_.u = (wrd);                                                        \
    STEP3((float)w_.h[0]);                                                       \
    STEP3((float)w_.h[1]); }

// ---------------------------------------------------------------------------
// Kernel 1 (unchanged from R18/R19 — ~14 us): MFMA Zc, Yc into transposed
// tiled layout [tile][64 s][8 halves]; fused from-rest 32-step state run per
// wave -> packed fb[run][lane][8]. Tail tiles zero-filled.
// ---------------------------------------------------------------------------
__global__ __launch_bounds__(256, 4) void k_mm(
    const float* __restrict__ Z, const float* __restrict__ Y,
    const float* __restrict__ C,
    const float* __restrict__ K_spike, const float* __restrict__ tau_spike,
    const float* __restrict__ delta_spike,
    _Float16* __restrict__ Zt, _Float16* __restrict__ Yt,
    float* __restrict__ fb, int T, int rgz, int NB)
{
    __shared__ _Float16 ztl[SUBS * LSTR];
    __shared__ _Float16 ytl[SUBS * LSTR];
    const int tid  = threadIdx.x;
    const int lane = tid & 63;
    const int wv   = tid >> 6;
    const int lr   = lane & 15;
    const int lg   = lane >> 4;
    const int t0b  = blockIdx.x * 128;

    int dl = (int)rintf(delta_spike[lane]);
    dl = min(max(dl, 0), 30);
    const bool alldl0 = __all(dl == 0);

    if (blockIdx.x == 0) {                    // fb guard runs (-8..-1)
        for (int idx = tid; idx < JT * 512; idx += 256) fb[idx] = 0.f;
    }
    if (!alldl0) {                            // guards only for fallback path
        if (blockIdx.x < 8) {
            const int tile = blockIdx.x * 4 + wv;
            uint4 z4 = {0, 0, 0, 0};
            ((uint4*)Zt)[(size_t)tile * 64 + lane] = z4;
            ((uint4*)Yt)[(size_t)tile * 64 + lane] = z4;
        } else if (blockIdx.x < 18) {
            const int tile = rgz + (blockIdx.x - 8) * 4 + wv;
            uint4 z4 = {0, 0, 0, 0};
            ((uint4*)Zt)[(size_t)tile * 64 + lane] = z4;
            ((uint4*)Yt)[(size_t)tile * 64 + lane] = z4;
        }
    }

    f16x8 bfr[4][2];
    #pragma unroll
    for (int nt = 0; nt < 4; ++nt)
        #pragma unroll
        for (int ks = 0; ks < 2; ++ks)
            bfr[nt][ks] = ld_frag(&C[(lr + 16 * nt) * 64 + ks * 32 + lg * 8]);

    #pragma unroll
    for (int g = 0; g < 2; ++g) {
        const int t0 = t0b + wv * 32 + g * 16;
        const int rowA = t0 + lr;
        const bool okA = rowA < T;
        f16x8 az[2], ay[2];
        #pragma unroll
        for (int ks = 0; ks < 2; ++ks) {
            if (okA) {
                az[ks] = ld_frag(&Z[(size_t)rowA * 64 + ks * 32 + lg * 8]);
                ay[ks] = ld_frag(&Y[(size_t)rowA * 64 + ks * 32 + lg * 8]);
            } else {
                az[ks] = (f16x8)(_Float16)0.f;
                ay[ks] = (f16x8)(_Float16)0.f;
            }
        }

        f32x4 accZ[4], accY[4];
        #pragma unroll
        for (int nt = 0; nt < 4; ++nt) { accZ[nt] = (f32x4){0,0,0,0}; accY[nt] = (f32x4){0,0,0,0}; }
        #pragma unroll
        for (int nt = 0; nt < 4; ++nt) {
            #pragma unroll
            for (int ks = 0; ks < 2; ++ks) {
                accZ[nt] = __builtin_amdgcn_mfma_f32_16x16x32_f16(az[ks], bfr[nt][ks], accZ[nt], 0, 0, 0);
                accY[nt] = __builtin_amdgcn_mfma_f32_16x16x32_f16(ay[ks], bfr[nt][ks], accY[nt], 0, 0, 0);
            }
        }

        #pragma unroll
        for (int nt = 0; nt < 4; ++nt) {
            const int sc = lr + 16 * nt;
            const int lt = wv * 32 + g * 16 + lg * 4;
            uint2 pz, py;
            pz.x = pkh2(accZ[nt][0], accZ[nt][1]);
            pz.y = pkh2(accZ[nt][2], accZ[nt][3]);
            py.x = pkh2(accY[nt][0], accY[nt][1]);
            py.y = pkh2(accY[nt][2], accY[nt][3]);
            *(uint2*)&ztl[sc * LSTR + lt] = pz;
            *(uint2*)&ytl[sc * LSTR + lt] = py;
        }
    }

    __syncthreads();

    // fused from-rest state run first (serial chain overlaps store latency)
    const int grun = blockIdx.x * 4 + wv;
    if (grun < NB) {
        float twr[3], mr2[3], cr[3];
        #pragma unroll
        for (int b = 0; b < 3; ++b) {
            const float tau = __expf(tau_spike[b]);
            const float r   = __expf(-1.0f / tau);
            twr[b] = 2.0f * r;
            mr2[b] = -r * r;
            cr[b]  = K_spike[lane * 3 + b] / tau * r;
        }
        const uint* zr = (const uint*)ztl + lane * (LSTR / 2) + wv * 16;
        float y1[3] = {0.f, 0.f, 0.f}, y2[3] = {0.f, 0.f, 0.f};
        #pragma unroll
        for (int k = 0; k < 16; ++k) PAIRW(zr[k]);
        float* fout = fb + (size_t)(grun + JT) * 512 + lane * 8;
        *(float4*)fout       = make_float4(y1[0], y2[0], y1[1], y2[1]);
        *(float2*)(fout + 4) = make_float2(y1[2], y2[2]);
    }

    // cooperative tiled stores (row = s fastest -> coalesced); tail zero-fill
    const int gbase = (GUARD >> 3) + blockIdx.x * 16;
    #pragma unroll
    for (int it = 0; it < 4; ++it) {
        const int chunk = it * 256 + tid;
        const int row = chunk & 63;
        const int col = chunk >> 6;
        const int tb  = t0b + col * 8;
        if (tb + 7 < T) {
            ((uint4*)Zt)[(size_t)(gbase + col) * 64 + row] =
                *(const uint4*)&ztl[row * LSTR + col * 8];
            ((uint4*)Yt)[(size_t)(gbase + col) * 64 + row] =
                *(const uint4*)&ytl[row * LSTR + col * 8];
        } else {
            union { ushort u[8]; uint4 v; } vz, vy;
            #pragma unroll
            for (int h = 0; h < 8; ++h) {
                const bool ok = (tb + h < T);
                vz.u[h] = ok ? ((const ushort*)ztl)[row * LSTR + col * 8 + h] : (ushort)0;
                vy.u[h] = ok ? ((const ushort*)ytl)[row * LSTR + col * 8 + h] : (ushort)0;
            }
            ((uint4*)Zt)[(size_t)(gbase + col) * 64 + row] = vz.v;
            ((uint4*)Yt)[(size_t)(gbase + col) * 64 + row] = vy.v;
        }
    }
}

// ---------------------------------------------------------------------------
// Kernel 2: Horner-compose v[32i] from packed fb, then 30 steps over 4
// aligned x tiles; out = sigmoid(Yc + S + theta + filt)*W + Vo.
// RULE #20 FIX: fast path has ZERO indexed local arrays — all S/Y/x words
// are named uint4 components consumed by fully-expanded macros (R18/R19:
// xw[]/ywd[]/spk[] were demoted to scratch -> WRITE 50000 KB, ~34 us).
// ---------------------------------------------------------------------------
#define OUTP(o, yh, ph, f) {                                                     \
    const int t_ = t0 + (o);                                                     \
    if (t_ < T) {                                                                \
        const float xin_ = (float)(yh) + (float)(ph) + (f);                      \
        const float sig_ = 1.0f / (1.0f + __expf(-xin_));                        \
        out[(size_t)t_ * 64 + s] = fmaf(sig_, wsub, vo);                         \
    } }

#define PW(xwrd, ywrd, swrd, ob) {                                               \
    uh2 wx_, wy_, wp_;                                                           \
    wx_.u = (xwrd); wy_.u = (ywrd); wp_.u = (swrd);                              \
    STEP3((float)wx_.h[0]);                                                      \
    OUTP((ob),     wy_.h[0], wp_.h[0], y1[0] + y1[1] + y1[2]);                   \
    STEP3((float)wx_.h[1]);                                                      \
    OUTP((ob) + 1, wy_.h[1], wp_.h[1], y1[0] + y1[1] + y1[2]); }

__global__ __launch_bounds__(256, 3) void k_iir2(
    const _Float16* __restrict__ Zt, const _Float16* __restrict__ Yt,
    const float* __restrict__ S,
    const float* __restrict__ K_spike, const float* __restrict__ tau_spike,
    const float* __restrict__ delta_spike, const float* __restrict__ theta,
    const float* __restrict__ W, const float* __restrict__ Vo,
    const float* __restrict__ fb, float* __restrict__ out, int T, int NB)
{
    const int tid = threadIdx.x;
    const int s   = tid & 63;
    const int wv  = tid >> 6;
    const int i   = blockIdx.x * 4 + wv;
    if (i >= NB) return;
    const int t0 = i * LB;

    float twr[3], mr2[3], cr[3], taus[3];
    #pragma unroll
    for (int b = 0; b < 3; ++b) {
        const float tau = __expf(tau_spike[b]);
        taus[b] = tau;
        const float r = __expf(-1.0f / tau);
        twr[b] = 2.0f * r;
        mr2[b] = -r * r;
        cr[b]  = K_spike[s * 3 + b] / tau * r;
    }
    int dl = (int)rintf(delta_spike[s]);
    dl = min(max(dl, 0), 30);
    const float th   = theta[s];
    const float wsub = W[s];
    const float vo   = Vo[0];

    if (__all(dl == 0) && (t0 + LB <= T)) {
        // ---- pack S + theta into named uint4s (coalesced; hides under Horner)
        const float* spp = S + (size_t)t0 * 64 + s;
        uint4 sp0, sp1, sp2, sp3;
        sp0.x = pkh2(spp[   0] + th, spp[  64] + th);
        sp0.y = pkh2(spp[ 128] + th, spp[ 192] + th);
        sp0.z = pkh2(spp[ 256] + th, spp[ 320] + th);
        sp0.w = pkh2(spp[ 384] + th, spp[ 448] + th);
        sp1.x = pkh2(spp[ 512] + th, spp[ 576] + th);
        sp1.y = pkh2(spp[ 640] + th, spp[ 704] + th);
        sp1.z = pkh2(spp[ 768] + th, spp[ 832] + th);
        sp1.w = pkh2(spp[ 896] + th, spp[ 960] + th);
        sp2.x = pkh2(spp[1024] + th, spp[1088] + th);
        sp2.y = pkh2(spp[1152] + th, spp[1216] + th);
        sp2.z = pkh2(spp[1280] + th, spp[1344] + th);
        sp2.w = pkh2(spp[1408] + th, spp[1472] + th);
        sp3.x = pkh2(spp[1536] + th, spp[1600] + th);
        sp3.y = pkh2(spp[1664] + th, spp[1728] + th);
        sp3.z = pkh2(spp[1792] + th, spp[1856] + th);
        sp3.w = pkh2(spp[1920] + th, spp[1984] + th);

        // ---- M^32 per basis: z[n+k] = (k+1) r^k z[n] - k r^(k+1) z[n-1]
        float aL[3], bL[3], cL[3], dL[3];
        #pragma unroll
        for (int b = 0; b < 3; ++b) {
            const float r   = 0.5f * twr[b];
            const float rm1 = __expf(-(float)(LB - 1) / taus[b]);  // r^31
            const float rl  = rm1 * r;                             // r^32
            const float rp  = rl * r;                              // r^33
            aL[b] = (float)(LB + 1) * rl;
            bL[b] = -(float)LB * rp;
            cL[b] = (float)LB * rm1;
            dL[b] = -(float)(LB - 1) * rl;
        }
        float y1[3], y2[3];
        {   // f_{i-8}
            const float* fq = fb + (size_t)i * 512 + s * 8;
            const float4 lo = *(const float4*)fq;
            const float2 hi = *(const float2*)(fq + 4);
            y1[0] = lo.x; y2[0] = lo.y; y1[1] = lo.z; y2[1] = lo.w;
            y1[2] = hi.x; y2[2] = hi.y;
        }
        #pragma unroll
        for (int j = 7; j >= 1; --j) {
            const float* fq = fb + (size_t)(i + JT - j) * 512 + s * 8;
            const float4 lo = *(const float4*)fq;
            const float2 hi = *(const float2*)(fq + 4);
            float n1, n2;
            n1 = fmaf(aL[0], y1[0], fmaf(bL[0], y2[0], lo.x));
            n2 = fmaf(cL[0], y1[0], fmaf(dL[0], y2[0], lo.y));
            y1[0] = n1; y2[0] = n2;
            n1 = fmaf(aL[1], y1[1], fmaf(bL[1], y2[1], lo.z));
            n2 = fmaf(cL[1], y1[1], fmaf(dL[1], y2[1], lo.w));
            y1[1] = n1; y2[1] = n2;
            n1 = fmaf(aL[2], y1[2], fmaf(bL[2], y2[2], hi.x));
            n2 = fmaf(cL[2], y1[2], fmaf(dL[2], y2[2], hi.y));
            y1[2] = n1; y2[2] = n2;
        }

        // ---- x / Yc tiles as named uint4s
        const uint4* xb = (const uint4*)Zt + (size_t)(32 + 4 * i) * 64 + s;
        const uint4 x0 = xb[0], x1 = xb[64], x2 = xb[128], x3 = xb[192];
        const uint4* yb = (const uint4*)Yt + (size_t)(32 + 4 * i) * 64 + s;
        const uint4 yv0 = yb[0], yv1 = yb[64], yv2 = yb[128], yv3 = yb[192];

        // outputs 0,1 from the composed state (word 0)
        {
            uh2 wy_, wp_;
            wy_.u = yv0.x; wp_.u = sp0.x;
            OUTP(0, wy_.h[0], wp_.h[0], y2[0] + y2[1] + y2[2]);
            OUTP(1, wy_.h[1], wp_.h[1], y1[0] + y1[1] + y1[2]);
        }
        // 30 steps, fully expanded: x-word w feeds output pair (2w+2, 2w+3)
        PW(x0.x, yv0.y, sp0.y,  2);  PW(x0.y, yv0.z, sp0.z,  4);
        PW(x0.z, yv0.w, sp0.w,  6);  PW(x0.w, yv1.x, sp1.x,  8);
        PW(x1.x, yv1.y, sp1.y, 10);  PW(x1.y, yv1.z, sp1.z, 12);
        PW(x1.z, yv1.w, sp1.w, 14);  PW(x1.w, yv2.x, sp2.x, 16);
        PW(x2.x, yv2.y, sp2.y, 18);  PW(x2.y, yv2.z, sp2.z, 20);
        PW(x2.z, yv2.w, sp2.w, 22);  PW(x2.w, yv3.x, sp3.x, 24);
        PW(x3.x, yv3.y, sp3.y, 26);  PW(x3.y, yv3.z, sp3.z, 28);
        PW(x3.z, yv3.w, sp3.w, 30);
    } else {
        // generic per-lane-delay path (correct, slow; unused for bench data)
        float y1[3] = {0.f, 0.f, 0.f}, y2[3] = {0.f, 0.f, 0.f};
        const int xi0 = t0 - 226 - dl;
        for (int k = 0; k < 224 + LB; ++k) {
            const int h = GUARD + xi0 + k;
            const float u = (float)Zt[(size_t)(h >> 3) * 512 + s * 8 + (h & 7)];
            STEP3(u);
            const int o = k - 224;
            if (o >= 0) {
                const int t = t0 + o;
                if (t < T) {
                    const int hy = GUARD + t;
                    const float yc = (float)Yt[(size_t)(hy >> 3) * 512 + s * 8 + (hy & 7)];
                    const float xin = yc + S[(size_t)t * 64 + s] + th
                                      + y1[0] + y1[1] + y1[2];
                    const float sig = 1.0f / (1.0f + __expf(-xin));
                    out[(size_t)t * 64 + s] = fmaf(sig, wsub, vo);
                }
            }
        }
    }
}

// ---------------------------------------------------------------------------
extern "C" void kernel_launch(void* const* d_in, const int* in_sizes, int n_in,
                              void* d_out, int out_size, void* d_ws, size_t ws_size,
                              hipStream_t stream)
{
    const float* S     = (const float*)d_in[0];
    const float* Y     = (const float*)d_in[1];
    const float* Z     = (const float*)d_in[2];
    const float* C     = (const float*)d_in[3];
    const float* Vo    = (const float*)d_in[4];
    const float* W     = (const float*)d_in[5];
    const float* theta = (const float*)d_in[6];
    const float* K     = (const float*)d_in[7];
    const float* tau   = (const float*)d_in[8];
    const float* delta = (const float*)d_in[9];
    const int T  = in_sizes[0] / SUBS;
    const int NB = (T + LB - 1) / LB;

    const int rgz    = (GUARD + T + 7) >> 3;
    const int ntiles = rgz + 44;
    _Float16* Zt = (_Float16*)d_ws;
    _Float16* Yt = (_Float16*)((char*)d_ws + (size_t)ntiles * 1024);
    float*    fb = (float*)((char*)d_ws + (size_t)ntiles * 2048);

    k_mm<<<(T + 127) / 128, 256, 0, stream>>>(Z, Y, C, K, tau, delta,
                                              Zt, Yt, fb, T, rgz, NB);
    k_iir2<<<(NB + 3) / 4, 256, 0, stream>>>(Zt, Yt, S, K, tau, delta, theta,
                                             W, Vo, fb, (float*)d_out, T, NB);
}